// Round 7
// baseline (31564.355 us; speedup 1.0000x reference)
//
#include <hip/hip_runtime.h>
#include <stdint.h>

typedef __fp16 f16x2 __attribute__((ext_vector_type(2)));
typedef __fp16 f16x8 __attribute__((ext_vector_type(8)));
typedef uint32_t u32x4 __attribute__((ext_vector_type(4)));
typedef unsigned long long ull;

#define SEQ  8192
#define HDIM 2048
#define DIN  256
#define DOUT 64

__device__ __forceinline__ f16x2 pk(float lo, float hi) {
    return __builtin_amdgcn_cvt_pkrtz(lo, hi);   // fp32 pair -> packed f16
}
__device__ __forceinline__ f16x2 pk2(float2 v) { return pk(v.x, v.y); }
__device__ __forceinline__ uint32_t h2u(f16x2 h) { return __builtin_bit_cast(uint32_t, h); }
__device__ __forceinline__ float sigf(float x) { return 1.0f / (1.0f + __expf(-x)); }
__device__ __forceinline__ float tanh_fast(float x) { return 2.0f * sigf(2.0f * x) - 1.0f; }

// LDS skews: chunk c's words land contiguously; chunks hit disjoint bank groups.
__device__ __forceinline__ int skH(int j) { return j + 4 * (j >> 7); }  // max 1051
__device__ __forceinline__ int skX(int j) { return j + 4 * (j >> 4); }  // max 155

// 32B poll load, MALL-coherent (sc1) — one RTT per sweep. Early-clobber: dest must not alias addr.
__device__ __forceinline__ void ld32_sc1(const ull* p, u32x4& a, u32x4& b) {
    asm volatile("global_load_dwordx4 %0, %2, off sc1\n\t"
                 "global_load_dwordx4 %1, %2, off offset:16 sc1\n\t"
                 "s_waitcnt vmcnt(0)"
                 : "=&v"(a), "=&v"(b) : "v"(p) : "memory");
}
// 32B poll load, own-XCD L2 (sc0 = SE scope: bypass L1, serve from L2)
__device__ __forceinline__ void ld32_sc0(const ull* p, u32x4& a, u32x4& b) {
    asm volatile("global_load_dwordx4 %0, %2, off sc0\n\t"
                 "global_load_dwordx4 %1, %2, off offset:16 sc0\n\t"
                 "s_waitcnt vmcnt(0)"
                 : "=&v"(a), "=&v"(b) : "v"(p) : "memory");
}
// 32B forward store into own-XCD L2
__device__ __forceinline__ void st32_sc0(ull* p, u32x4 a, u32x4 b) {
    asm volatile("global_store_dwordx4 %2, %0, off sc0\n\t"
                 "global_store_dwordx4 %2, %1, off offset:16 sc0"
                 :: "v"(a), "v"(b), "v"(p) : "memory");
}

__global__ void __launch_bounds__(256, 1)
lstm_persist(const float2* __restrict__ x2,       // [8192*128] fp32 pairs
             const float2* __restrict__ hprev2,   // [1024]
             const float*  __restrict__ cprev,    // [2048]
             const float*  __restrict__ wih,      // [8192*256]
             const float*  __restrict__ whh,      // [8192*2048]
             const float*  __restrict__ bih,      // [8192]
             const float*  __restrict__ bhh,      // [8192]
             const float2* __restrict__ wfc2,     // [64*1024]
             const float*  __restrict__ bfc,      // [64]
             float* __restrict__ out,             // 528384 fp32
             uint32_t* __restrict__ hs_w,         // [256 blocks][32 rows][1024 words] PRIVATE
             ull* __restrict__ htag,              // [2][1024] global tagged-word mailbox
             ull* __restrict__ xcdbuf,            // [8 grp][2][1024] per-XCD relay buffers
             uint32_t* __restrict__ cnt)          // [8] relay-election counters (zeroed)
{
    const int tid = threadIdx.x;
    const int b   = blockIdx.x;
    const int wv  = tid >> 6;        // wave id 0..3 -> units 2wv, 2wv+1
    const int l   = tid & 63;        // lane
    const int g   = l >> 4;          // gate 0..3 (i,f,g,o)
    const int p   = (l >> 3) & 1;    // unit parity
    const int c   = l & 7;           // k-chunk 0..7

    __shared__ __align__(16) uint32_t smem[12672];
    uint32_t* ldsH0 = smem;            // 1056 words
    uint32_t* ldsH1 = smem + 1056;     // 1056
    uint32_t* ldsX  = smem + 2112;     // 160
    // FC-phase reuse:
    uint32_t* hsl = smem;              // 32*132
    uint32_t* wfl = smem + 4224;       // 64*132

    __shared__ int sh_grp, sh_slot;

    uint32_t* hs_priv = hs_w + (size_t)b * 32 * 1024;   // this block's FC rows

    // ---------------- relay election (one relay per XCD group) ----------------
    if (tid == 0) {
        uint32_t xcc;
        asm volatile("s_getreg_b32 %0, hwreg(HW_REG_XCC_ID, 0, 32)" : "=s"(xcc));
        int gidx = (int)(xcc & 7u);
        sh_grp  = gidx;
        sh_slot = (int)atomicAdd(cnt + gidx, 1u);   // device-scope, MALL-coherent
    }

    // ---------------- prologue: weights -> registers (fp32 -> f16) ----------------
    const int unit = 8 * b + 2 * wv + p;          // this lane's hidden unit
    const int r    = g * 2048 + unit;             // this lane's gate-row
    f16x2 wh[128];                                // W_hh[r, 256c .. 256c+256)
    {
        const float4* ptr = (const float4*)(whh + (size_t)r * 2048 + 256 * c);
#pragma unroll
        for (int q = 0; q < 64; ++q) {
            float4 v = ptr[q];
            wh[2*q+0] = pk(v.x, v.y);
            wh[2*q+1] = pk(v.z, v.w);
        }
    }
    f16x2 wx[16];                                 // W_ih[r, 32c .. 32c+32)
    {
        const float4* ptr = (const float4*)(wih + (size_t)r * 256 + 32 * c);
#pragma unroll
        for (int q = 0; q < 8; ++q) {
            float4 v = ptr[q];
            wx[2*q+0] = pk(v.x, v.y);
            wx[2*q+1] = pk(v.z, v.w);
        }
    }
    // h version 0 (hprev) -> slot 0 ; x row 0 -> ldsX
#pragma unroll
    for (int k = 0; k < 4; ++k) {
        int j = tid + 256 * k;
        ldsH0[skH(j)] = h2u(pk2(hprev2[j]));
    }
    if (tid < 128) ldsX[skX(tid)] = h2u(pk2(x2[tid]));

    float cloc = cprev[unit];
    float hloc = 0.f;
    const float bsum = bih[r] + bhh[r];             // per-lane gate bias
    const ull deadline = __builtin_amdgcn_s_memrealtime() + 60000000ull; // watchdog: bail, no hang
    __syncthreads();
    const int  grp   = sh_grp;
    const bool relay = (sh_slot == 0);
    bool mb_fb = false;   // sticky: if relay forwards are invisible, poll mailbox directly forever

    // ---------------- sequential scan: ONE barrier per step ----------------
    for (int t = 0; t < SEQ; ++t) {
        uint32_t* ldsH = (t & 1) ? ldsH1 : ldsH0;

        // x-projection (off critical path), 8-way ILP accumulators
        float accs[8];
#pragma unroll
        for (int q = 0; q < 8; ++q) accs[q] = 0.f;
        {
            const f16x8* xp = (const f16x8*)(ldsX + 20 * c);
#pragma unroll
            for (int q = 0; q < 4; ++q) {
                f16x8 xv = xp[q];
#pragma unroll
                for (int d = 0; d < 4; ++d) {
                    f16x2 hv = {xv[2*d], xv[2*d+1]};
                    int idx = 4 * q + d;
                    accs[idx & 7] = __builtin_amdgcn_fdot2(wx[idx], hv, accs[idx & 7], false);
                }
            }
        }
        // prefetch next x row (consumed after the barrier)
        float2 xw = {0.f, 0.f};
        const bool xl = (tid < 128) && (t + 1 < SEQ);
        if (xl) xw = x2[(size_t)(t + 1) * 128 + tid];

        // exchange: thread tid handles the 4 words of producer block `tid` (32B quad)
        if (t > 0) {
            const int par = t & 1;
            u32x4 qa, qb;
            const ull* mb = htag + (size_t)par * 1024 + 4 * tid;
            if (relay) {
                int spins = 0;
                for (;;) {
                    ld32_sc1(mb, qa, qb);
                    if (qa[1] == (uint32_t)t && qa[3] == (uint32_t)t &&
                        qb[1] == (uint32_t)t && qb[3] == (uint32_t)t) break;
                    if (spins++ > 0) {
                        if (__builtin_amdgcn_s_memrealtime() > deadline) break;
                        __builtin_amdgcn_s_sleep(1);
                    }
                }
                st32_sc0(xcdbuf + ((size_t)grp * 2 + par) * 1024 + 4 * tid, qa, qb);
            } else {
                const ull* xb = xcdbuf + ((size_t)grp * 2 + par) * 1024 + 4 * tid;
                int spins = 0;
                for (;;) {
                    if (!mb_fb) ld32_sc0(xb, qa, qb);
                    else        ld32_sc1(mb, qa, qb);
                    if (qa[1] == (uint32_t)t && qa[3] == (uint32_t)t &&
                        qb[1] == (uint32_t)t && qb[3] == (uint32_t)t) break;
                    ++spins;
                    if (!mb_fb) {
                        if (spins > 64) mb_fb = true;   // relay invisible -> direct, forever
                    } else {
                        if (__builtin_amdgcn_s_memrealtime() > deadline) break;
                        __builtin_amdgcn_s_sleep(1);
                    }
                }
            }
            u32x4 pays = {qa[0], qa[2], qb[0], qb[2]};
            *(u32x4*)(ldsH + skH(4 * tid)) = pays;          // contiguous quad -> ds_write_b128
            if (((t - 1) >> 5) == b)
                *(u32x4*)(hs_priv + (size_t)((t - 1) & 31) * 1024 + 4 * tid) = pays;
        }
        __syncthreads();
        if (xl) ldsX[skX(tid)] = h2u(pk2(xw));   // consumed next step, after waves re-converge

        // recurrent matvec from register weights, h via LDS broadcast (8-way ILP)
        {
            const f16x8* hp = (const f16x8*)(ldsH + 132 * c);
#pragma unroll
            for (int q = 0; q < 32; ++q) {
                f16x8 hv8 = hp[q];
#pragma unroll
                for (int d = 0; d < 4; ++d) {
                    f16x2 hh = {hv8[2*d], hv8[2*d+1]};
                    int idx = 4 * q + d;
                    accs[idx & 7] = __builtin_amdgcn_fdot2(wh[idx], hh, accs[idx & 7], false);
                }
            }
        }
        float acc = ((accs[0] + accs[1]) + (accs[2] + accs[3]))
                  + ((accs[4] + accs[5]) + (accs[6] + accs[7]));
        // reduce over the 8 k-chunk lanes (c = bits 0..2 of lane)
        acc += __shfl_xor(acc, 1);
        acc += __shfl_xor(acc, 2);
        acc += __shfl_xor(acc, 4);

        // one v_exp for all four gates (lane-specialized), then intra-wave gather
        float z = acc + bsum;
        const bool isg = (g == 2);
        float s  = sigf(isg ? 2.0f * z : z);
        float val = isg ? (2.0f * s - 1.0f) : s;
        const int p8 = l & 8;
        float iv = __shfl(val, p8 + 0);
        float fv = __shfl(val, p8 + 16);
        float gv = __shfl(val, p8 + 32);
        float ov = __shfl(val, p8 + 48);
        cloc = fv * cloc + iv * gv;
        hloc = ov * tanh_fast(cloc);

        // publish: pack (h_unit2wv, h_unit2wv+1) with tag t+1 — one 8B word per wave
        float h0 = __shfl(hloc, 0);
        float h1 = __shfl(hloc, 8);
        uint32_t pay = h2u(pk(h0, h1));
        if (l == 0) {
            ull tv = ((ull)(uint32_t)(t + 1) << 32) | (ull)pay;
            __hip_atomic_store(htag + (size_t)((t + 1) & 1) * 1024 + 4 * b + wv,
                               tv, __ATOMIC_RELAXED, __HIP_MEMORY_SCOPE_AGENT);
        }
    }

    // hT / cT outputs (fp32): lanes 0 (p=0) and 8 (p=1) of each wave hold their unit
    if (l == 0 || l == 8) {
        out[(size_t)SEQ * DOUT + unit]        = hloc;
        out[(size_t)SEQ * DOUT + HDIM + unit] = cloc;
    }

    // only block 255 needs h(8191) (= hs row 8191) -> poll tag 8192 (slot 0) on the mailbox
    if (b == 255) {
        uint32_t pay[4] = {0, 0, 0, 0};
        unsigned got = 0;
        while (got != 0xFu) {
#pragma unroll
            for (int k = 0; k < 4; ++k) {
                if (!(got & (1u << k))) {
                    ull v = __hip_atomic_load(htag + (tid + 256 * k),
                                              __ATOMIC_RELAXED, __HIP_MEMORY_SCOPE_AGENT);
                    if ((uint32_t)(v >> 32) == 8192u) {
                        pay[k] = (uint32_t)v;
                        got |= (1u << k);
                    }
                }
            }
            if (got != 0xFu) {
                if (__builtin_amdgcn_s_memrealtime() > deadline) got = 0xFu;
                __builtin_amdgcn_s_sleep(1);
            }
        }
#pragma unroll
        for (int k = 0; k < 4; ++k)
            hs_priv[(size_t)31 * 1024 + tid + 256 * k] = pay[k];
    }
    __syncthreads();

    // ---------------- output FC: rows [32b, 32b+32), 64 cols, from PRIVATE hs ----------------
    const int cc = tid & 63;
    const int rg = tid >> 6;
    const float bo = bfc[cc];
    float fca[8];
#pragma unroll
    for (int q = 0; q < 8; ++q) fca[q] = 0.f;

    for (int ch = 0; ch < 8; ++ch) {   // 8 chunks of 256 k (128 pair-words)
#pragma unroll
        for (int i = 0; i < 16; ++i) { // hs tile: [32 rows][128 words]
            int idx = tid + 256 * i;
            int rr = idx >> 7, kp = idx & 127;
            hsl[rr * 132 + kp] = hs_priv[(size_t)rr * 1024 + ch * 128 + kp]; // own writes
        }
#pragma unroll
        for (int i = 0; i < 32; ++i) { // W_fc tile: [64 cols][128 pair-words]
            int idx = tid + 256 * i;
            int c2 = idx >> 7, kp = idx & 127;
            wfl[c2 * 132 + kp] = h2u(pk2(wfc2[(size_t)c2 * 1024 + ch * 128 + kp]));
        }
        __syncthreads();
#pragma unroll 4
        for (int k4 = 0; k4 < 32; ++k4) {
            f16x8 wvv = *(const f16x8*)(wfl + cc * 132 + 4 * k4);
#pragma unroll
            for (int q = 0; q < 8; ++q) {
                f16x8 hv = *(const f16x8*)(hsl + (rg * 8 + q) * 132 + 4 * k4);
#pragma unroll
                for (int d = 0; d < 4; ++d) {
                    f16x2 a  = {hv[2*d], hv[2*d+1]};
                    f16x2 bb = {wvv[2*d], wvv[2*d+1]};
                    fca[q] = __builtin_amdgcn_fdot2(a, bb, fca[q], false);
                }
            }
        }
        __syncthreads();
    }
#pragma unroll
    for (int q = 0; q < 8; ++q) {
        size_t row = (size_t)32 * b + rg * 8 + q;
        out[row * DOUT + cc] = sigf(fca[q] + bo);
    }
}

extern "C" void kernel_launch(void* const* d_in, const int* in_sizes, int n_in,
                              void* d_out, int out_size, void* d_ws, size_t ws_size,
                              hipStream_t stream) {
    const float2* x2     = (const float2*)d_in[0];
    const float2* hprev2 = (const float2*)d_in[1];
    const float*  cprev  = (const float*)d_in[2];
    const float*  wih    = (const float*)d_in[3];
    const float*  whh    = (const float*)d_in[4];
    const float*  bih    = (const float*)d_in[5];
    const float*  bhh    = (const float*)d_in[6];
    const float2* wfc2   = (const float2*)d_in[7];
    const float*  bfc    = (const float*)d_in[8];
    float*        out    = (float*)d_out;

    char* ws = (char*)d_ws;
    uint32_t* hs_w   = (uint32_t*)ws;                              // 33,554,432 B
    ull*      htag   = (ull*)(ws + 33554432);                      // 16 KB (0xAA != any tag)
    ull*      xcdbuf = (ull*)(ws + 33554432 + 16384);              // 128 KB (0xAA != any tag)
    uint32_t* cnt    = (uint32_t*)(ws + 33554432 + 16384 + 131072); // 32 B, must be zeroed

    hipMemsetAsync(cnt, 0, 32, stream);   // graph-capturable
    lstm_persist<<<dim3(256), dim3(256), 0, stream>>>(
        x2, hprev2, cprev, wih, whh, bih, bhh, wfc2, bfc,
        out, hs_w, htag, xcdbuf, cnt);
}

// Round 8
// 23093.785 us; speedup vs baseline: 1.3668x; 1.3668x over previous
//
#include <hip/hip_runtime.h>
#include <stdint.h>

typedef __fp16 f16x2 __attribute__((ext_vector_type(2)));
typedef __fp16 f16x8 __attribute__((ext_vector_type(8)));
typedef uint32_t u32x4 __attribute__((ext_vector_type(4)));
typedef unsigned long long ull;

#define SEQ  8192
#define HDIM 2048
#define DIN  256
#define DOUT 64

__device__ __forceinline__ f16x2 pk(float lo, float hi) {
    return __builtin_amdgcn_cvt_pkrtz(lo, hi);   // fp32 pair -> packed f16
}
__device__ __forceinline__ f16x2 pk2(float2 v) { return pk(v.x, v.y); }
__device__ __forceinline__ uint32_t h2u(f16x2 h) { return __builtin_bit_cast(uint32_t, h); }
__device__ __forceinline__ float sigf(float x) { return 1.0f / (1.0f + __expf(-x)); }
__device__ __forceinline__ float tanh_fast(float x) { return 2.0f * sigf(2.0f * x) - 1.0f; }

// LDS skews: chunk c's words land contiguously; chunks hit disjoint bank groups.
__device__ __forceinline__ int skH(int j) { return j + 4 * (j >> 7); }  // max 1051
__device__ __forceinline__ int skX(int j) { return j + 4 * (j >> 4); }  // max 155

// 32B load, MALL-coherent (sc1), single RTT; early-clobber so dest never aliases addr.
__device__ __forceinline__ void ld32_sc1(const ull* p, u32x4& a, u32x4& b) {
    asm volatile("global_load_dwordx4 %0, %2, off sc1\n\t"
                 "global_load_dwordx4 %1, %2, off offset:16 sc1\n\t"
                 "s_waitcnt vmcnt(0)"
                 : "=&v"(a), "=&v"(b) : "v"(p) : "memory");
}
// 4B counter load, MALL-coherent
__device__ __forceinline__ uint32_t ld_ctr(const uint32_t* p) {
    uint32_t v;
    asm volatile("global_load_dword %0, %1, off sc1\n\t"
                 "s_waitcnt vmcnt(0)"
                 : "=&v"(v) : "v"(p) : "memory");
    return v;
}

__global__ void __launch_bounds__(256, 1)
lstm_persist(const float2* __restrict__ x2,       // [8192*128] fp32 pairs
             const float2* __restrict__ hprev2,   // [1024]
             const float*  __restrict__ cprev,    // [2048]
             const float*  __restrict__ wih,      // [8192*256]
             const float*  __restrict__ whh,      // [8192*2048]
             const float*  __restrict__ bih,      // [8192]
             const float*  __restrict__ bhh,      // [8192]
             const float2* __restrict__ wfc2,     // [64*1024]
             const float*  __restrict__ bfc,      // [64]
             float* __restrict__ out,             // 528384 fp32
             uint32_t* __restrict__ hs_w,         // [256 blocks][32 rows][1024 words] PRIVATE
             ull* __restrict__ htag,              // [2][1024] tagged-word mailbox
             uint32_t* __restrict__ ctr)          // [2 parity][8] counters, 512B stride, zeroed
{
    const int tid = threadIdx.x;
    const int b   = blockIdx.x;
    const int wv  = tid >> 6;        // wave id 0..3 -> units 2wv, 2wv+1
    const int l   = tid & 63;        // lane
    const int g   = l >> 4;          // gate 0..3 (i,f,g,o)
    const int p   = (l >> 3) & 1;    // unit parity
    const int c   = l & 7;           // k-chunk 0..7

    __shared__ __align__(16) uint32_t smem[12672];
    uint32_t* ldsH0 = smem;            // 1056 words
    uint32_t* ldsH1 = smem + 1056;     // 1056
    uint32_t* ldsX  = smem + 2112;     // 160
    // FC-phase reuse:
    uint32_t* hsl = smem;              // 32*132
    uint32_t* wfl = smem + 4224;       // 64*132

    uint32_t* hs_priv = hs_w + (size_t)b * 32 * 1024;   // this block's FC rows

    // ---------------- prologue: weights -> registers (fp32 -> f16) ----------------
    const int unit = 8 * b + 2 * wv + p;          // this lane's hidden unit
    const int r    = g * 2048 + unit;             // this lane's gate-row
    f16x2 wh[128];                                // W_hh[r, 256c .. 256c+256)
    {
        const float4* ptr = (const float4*)(whh + (size_t)r * 2048 + 256 * c);
#pragma unroll
        for (int q = 0; q < 64; ++q) {
            float4 v = ptr[q];
            wh[2*q+0] = pk(v.x, v.y);
            wh[2*q+1] = pk(v.z, v.w);
        }
    }
    f16x2 wx[16];                                 // W_ih[r, 32c .. 32c+32)
    {
        const float4* ptr = (const float4*)(wih + (size_t)r * 256 + 32 * c);
#pragma unroll
        for (int q = 0; q < 8; ++q) {
            float4 v = ptr[q];
            wx[2*q+0] = pk(v.x, v.y);
            wx[2*q+1] = pk(v.z, v.w);
        }
    }
    // h version 0 (hprev) -> slot 0 ; x row 0 -> ldsX
#pragma unroll
    for (int k = 0; k < 4; ++k) {
        int j = tid + 256 * k;
        ldsH0[skH(j)] = h2u(pk2(hprev2[j]));
    }
    if (tid < 128) ldsX[skX(tid)] = h2u(pk2(x2[tid]));

    float cloc = cprev[unit];
    float hloc = 0.f;
    const float bsum = bih[r] + bhh[r];             // per-lane gate bias
    const ull deadline = __builtin_amdgcn_s_memrealtime() + 60000000ull; // watchdog: bail, no hang
    __syncthreads();

    // ---------------- sequential scan: ONE barrier per step ----------------
    for (int t = 0; t < SEQ; ++t) {
        uint32_t* ldsH = (t & 1) ? ldsH1 : ldsH0;

        // x-projection (off critical path), 8-way ILP accumulators
        float accs[8];
#pragma unroll
        for (int q = 0; q < 8; ++q) accs[q] = 0.f;
        {
            const f16x8* xp = (const f16x8*)(ldsX + 20 * c);
#pragma unroll
            for (int q = 0; q < 4; ++q) {
                f16x8 xv = xp[q];
#pragma unroll
                for (int d = 0; d < 4; ++d) {
                    f16x2 hv = {xv[2*d], xv[2*d+1]};
                    int idx = 4 * q + d;
                    accs[idx & 7] = __builtin_amdgcn_fdot2(wx[idx], hv, accs[idx & 7], false);
                }
            }
        }
        // prefetch next x row (consumed after the barrier)
        float2 xw = {0.f, 0.f};
        const bool xl = (tid < 128) && (t + 1 < SEQ);
        if (xl) xw = x2[(size_t)(t + 1) * 128 + tid];

        // ---- exchange ----
        if (t > 0) {
            const int par = t & 1;
            // 1) cheap readiness gate: poll 8 striped counters (8 tx/block/sweep)
            const uint32_t target = (uint32_t)((t + (t & 1)) >> 1) * 32u;
            const uint32_t* cbase = ctr + (size_t)par * 8 * 128;
            int spins = 0;
            for (;;) {
                uint32_t v = 0xFFFFFFFFu;
                if (l < 8) v = ld_ctr(cbase + (size_t)l * 128);
                bool ok = (l >= 8) || (v >= target);
                if (__all(ok)) break;
                if (spins++ > 0) {
                    if (__builtin_amdgcn_s_memrealtime() > deadline) break;
                    __builtin_amdgcn_s_sleep(1);
                }
            }
            // 2) one-shot data read (32B quad = producer block tid's 4 words), tag-validated
            const ull* mb = htag + (size_t)par * 1024 + 4 * tid;
            u32x4 qa, qb;
            for (;;) {
                ld32_sc1(mb, qa, qb);
                if (qa[1] == (uint32_t)t && qa[3] == (uint32_t)t &&
                    qb[1] == (uint32_t)t && qb[3] == (uint32_t)t) break;
                if (__builtin_amdgcn_s_memrealtime() > deadline) break;
                __builtin_amdgcn_s_sleep(1);
            }
            u32x4 pays = {qa[0], qa[2], qb[0], qb[2]};
            *(u32x4*)(ldsH + skH(4 * tid)) = pays;          // contiguous quad -> ds_write_b128
            if (((t - 1) >> 5) == b)
                *(u32x4*)(hs_priv + (size_t)((t - 1) & 31) * 1024 + 4 * tid) = pays;
        }
        __syncthreads();
        if (xl) ldsX[skX(tid)] = h2u(pk2(xw));   // consumed next step, after waves re-converge

        // recurrent matvec from register weights, h via LDS broadcast (8-way ILP)
        {
            const f16x8* hp = (const f16x8*)(ldsH + 132 * c);
#pragma unroll
            for (int q = 0; q < 32; ++q) {
                f16x8 hv8 = hp[q];
#pragma unroll
                for (int d = 0; d < 4; ++d) {
                    f16x2 hh = {hv8[2*d], hv8[2*d+1]};
                    int idx = 4 * q + d;
                    accs[idx & 7] = __builtin_amdgcn_fdot2(wh[idx], hh, accs[idx & 7], false);
                }
            }
        }
        float acc = ((accs[0] + accs[1]) + (accs[2] + accs[3]))
                  + ((accs[4] + accs[5]) + (accs[6] + accs[7]));
        // reduce over the 8 k-chunk lanes (c = bits 0..2 of lane)
        acc += __shfl_xor(acc, 1);
        acc += __shfl_xor(acc, 2);
        acc += __shfl_xor(acc, 4);

        // one v_exp for all four gates (lane-specialized), then intra-wave gather
        float z = acc + bsum;
        const bool isg = (g == 2);
        float s  = sigf(isg ? 2.0f * z : z);
        float val = isg ? (2.0f * s - 1.0f) : s;
        const int p8 = l & 8;
        float iv = __shfl(val, p8 + 0);
        float fv = __shfl(val, p8 + 16);
        float gv = __shfl(val, p8 + 32);
        float ov = __shfl(val, p8 + 48);
        cloc = fv * cloc + iv * gv;
        hloc = ov * tanh_fast(cloc);

        // publish: tagged word per wave, then one counter bump per block (hint only)
        float h0 = __shfl(hloc, 0);
        float h1 = __shfl(hloc, 8);
        uint32_t pay = h2u(pk(h0, h1));
        if (l == 0) {
            ull tv = ((ull)(uint32_t)(t + 1) << 32) | (ull)pay;
            __hip_atomic_store(htag + (size_t)((t + 1) & 1) * 1024 + 4 * b + wv,
                               tv, __ATOMIC_RELAXED, __HIP_MEMORY_SCOPE_AGENT);
            if (wv == 0)
                atomicAdd(ctr + ((size_t)((t + 1) & 1) * 8 + (b & 7)) * 128, 1u);
        }
    }

    // hT / cT outputs (fp32): lanes 0 (p=0) and 8 (p=1) of each wave hold their unit
    if (l == 0 || l == 8) {
        out[(size_t)SEQ * DOUT + unit]        = hloc;
        out[(size_t)SEQ * DOUT + HDIM + unit] = cloc;
    }

    // only block 255 needs h(8191) (= hs row 8191) -> poll tag 8192 (slot 0) on the mailbox
    if (b == 255) {
        uint32_t pay[4] = {0, 0, 0, 0};
        unsigned got = 0;
        while (got != 0xFu) {
#pragma unroll
            for (int k = 0; k < 4; ++k) {
                if (!(got & (1u << k))) {
                    ull v = __hip_atomic_load(htag + (tid + 256 * k),
                                              __ATOMIC_RELAXED, __HIP_MEMORY_SCOPE_AGENT);
                    if ((uint32_t)(v >> 32) == 8192u) {
                        pay[k] = (uint32_t)v;
                        got |= (1u << k);
                    }
                }
            }
            if (got != 0xFu) {
                if (__builtin_amdgcn_s_memrealtime() > deadline) got = 0xFu;
                __builtin_amdgcn_s_sleep(1);
            }
        }
#pragma unroll
        for (int k = 0; k < 4; ++k)
            hs_priv[(size_t)31 * 1024 + tid + 256 * k] = pay[k];
    }
    __syncthreads();

    // ---------------- output FC: rows [32b, 32b+32), 64 cols, from PRIVATE hs ----------------
    const int cc = tid & 63;
    const int rg = tid >> 6;
    const float bo = bfc[cc];
    float fca[8];
#pragma unroll
    for (int q = 0; q < 8; ++q) fca[q] = 0.f;

    for (int ch = 0; ch < 8; ++ch) {   // 8 chunks of 256 k (128 pair-words)
#pragma unroll
        for (int i = 0; i < 16; ++i) { // hs tile: [32 rows][128 words]
            int idx = tid + 256 * i;
            int rr = idx >> 7, kp = idx & 127;
            hsl[rr * 132 + kp] = hs_priv[(size_t)rr * 1024 + ch * 128 + kp]; // own writes
        }
#pragma unroll
        for (int i = 0; i < 32; ++i) { // W_fc tile: [64 cols][128 pair-words]
            int idx = tid + 256 * i;
            int c2 = idx >> 7, kp = idx & 127;
            wfl[c2 * 132 + kp] = h2u(pk2(wfc2[(size_t)c2 * 1024 + ch * 128 + kp]));
        }
        __syncthreads();
#pragma unroll 4
        for (int k4 = 0; k4 < 32; ++k4) {
            f16x8 wvv = *(const f16x8*)(wfl + cc * 132 + 4 * k4);
#pragma unroll
            for (int q = 0; q < 8; ++q) {
                f16x8 hv = *(const f16x8*)(hsl + (rg * 8 + q) * 132 + 4 * k4);
#pragma unroll
                for (int d = 0; d < 4; ++d) {
                    f16x2 a  = {hv[2*d], hv[2*d+1]};
                    f16x2 bb = {wvv[2*d], wvv[2*d+1]};
                    fca[q] = __builtin_amdgcn_fdot2(a, bb, fca[q], false);
                }
            }
        }
        __syncthreads();
    }
#pragma unroll
    for (int q = 0; q < 8; ++q) {
        size_t row = (size_t)32 * b + rg * 8 + q;
        out[row * DOUT + cc] = sigf(fca[q] + bo);
    }
}

extern "C" void kernel_launch(void* const* d_in, const int* in_sizes, int n_in,
                              void* d_out, int out_size, void* d_ws, size_t ws_size,
                              hipStream_t stream) {
    const float2* x2     = (const float2*)d_in[0];
    const float2* hprev2 = (const float2*)d_in[1];
    const float*  cprev  = (const float*)d_in[2];
    const float*  wih    = (const float*)d_in[3];
    const float*  whh    = (const float*)d_in[4];
    const float*  bih    = (const float*)d_in[5];
    const float*  bhh    = (const float*)d_in[6];
    const float2* wfc2   = (const float2*)d_in[7];
    const float*  bfc    = (const float*)d_in[8];
    float*        out    = (float*)d_out;

    char* ws = (char*)d_ws;
    uint32_t* hs_w = (uint32_t*)ws;                      // 33,554,432 B private hs slices
    ull*      htag = (ull*)(ws + 33554432);              // 16 KB (0xAA != any tag)
    uint32_t* ctr  = (uint32_t*)(ws + 33554432 + 16384); // 16 ctrs x 512B stride = 8 KB, zeroed

    hipMemsetAsync(ctr, 0, 8192, stream);   // graph-capturable
    lstm_persist<<<dim3(256), dim3(256), 0, stream>>>(
        x2, hprev2, cprev, wih, whh, bih, bhh, wfc2, bfc,
        out, hs_w, htag, ctr);
}